// Round 12
// baseline (135.552 us; speedup 1.0000x reference)
//
#include <hip/hip_runtime.h>
#include <math.h>

#define S_LEN 2049
#define P_LEN 2048
#define EMB 512
#define NH 8
#define HD 64
#define SCALE 0.125f

typedef _Float16 f16x8 __attribute__((ext_vector_type(8)));
typedef float f32x4 __attribute__((ext_vector_type(4)));
typedef unsigned short u16x8 __attribute__((ext_vector_type(8)));

__device__ inline unsigned short f2h(float f) {
  _Float16 h = (_Float16)f;  // RNE
  return __builtin_bit_cast(unsigned short, h);
}
__device__ inline float h2f(unsigned short u) {
  return (float)__builtin_bit_cast(_Float16, u);
}

// async global->LDS, 16B per lane; LDS dest = wave-uniform base + lane*16
__device__ inline void gld16(const unsigned* g, unsigned* l) {
  __builtin_amdgcn_global_load_lds(
      (const __attribute__((address_space(1))) unsigned*)g,
      (__attribute__((address_space(3))) unsigned*)l, 16, 0, 0);
}

// fused fp32 -> fp16 converter for the three operands (x, qkv_w, out_w).
// Also zeroes the 16 cls-combine counters (ws is poisoned 0xAA every launch;
// stream order guarantees this precedes the attention kernel's atomics).
__global__ __launch_bounds__(256) void cvt3_f16(
    const float* __restrict__ s0, unsigned short* __restrict__ d0, int n0,
    const float* __restrict__ s1, unsigned short* __restrict__ d1, int n1,
    const float* __restrict__ s2, unsigned short* __restrict__ d2, int n2,
    unsigned* __restrict__ counters) {
  if (blockIdx.x == 0 && threadIdx.x < 16) counters[threadIdx.x] = 0;
  int idx = (blockIdx.x * 256 + threadIdx.x) * 8;
  const float* s;
  unsigned short* d;
  int off;
  if (idx < n0) {
    s = s0; d = d0; off = idx;
  } else if (idx < n0 + n1) {
    s = s1; d = d1; off = idx - n0;
  } else if (idx < n0 + n1 + n2) {
    s = s2; d = d2; off = idx - n0 - n1;
  } else {
    return;
  }
  float4 f0 = *(const float4*)(s + off);
  float4 f1 = *(const float4*)(s + off + 4);
  float ff[8] = {f0.x, f0.y, f0.z, f0.w, f1.x, f1.y, f1.z, f1.w};
  u16x8 vh;
#pragma unroll
  for (int e = 0; e < 8; e++) vh[e] = f2h(ff[e]);
  *(u16x8*)(d + off) = vh;
}

// Plain fp16 GEMM, m97 structure, BK=64 (round-9/11 proven; BK=128 regressed
// per round-10 + m132: 48KB LDS cut blocks/CU and lengthened barrier drains).
template <int BM, int BN, bool F16OUT>
__global__ __launch_bounds__(256) void gemm_f16(
    const unsigned short* __restrict__ A, const unsigned short* __restrict__ B,
    const float* __restrict__ bias, void* __restrict__ Cv, int M, int N,
    int KP) {
  constexpr int BK = 64;
  __shared__ __align__(16) unsigned short As[BM * BK];
  __shared__ __align__(16) unsigned short Bs[BN * BK];
  const int t = threadIdx.x;
  const int lane = t & 63, wv = t >> 6;
  const int m0 = blockIdx.x * BM, n0 = blockIdx.y * BN;
  constexpr int WM = BM / 2, WN = BN / 2;
  constexpr int RM = WM / 16, RN = WN / 16;
  const int wm = wv & 1, wn = wv >> 1;
  const int lm = lane & 15, lq = lane >> 4;

  f32x4 acc[RM][RN];
#pragma unroll
  for (int i = 0; i < RM; i++)
#pragma unroll
    for (int j = 0; j < RN; j++) acc[i][j] = (f32x4){0.f, 0.f, 0.f, 0.f};

  const int lr = lane >> 3;
  const int lc = (lane & 7) ^ lr;  // XOR-swizzled source chunk (bank spread)

  const unsigned* aptr[BM / 32];
#pragma unroll
  for (int p = 0; p < BM / 32; p++) {
    int ra = wv * (BM / 4) + p * 8 + lr;
    int gr = m0 + ra;
    gr = gr < M ? gr : M - 1;  // clamp source (epilogue store is guarded)
    aptr[p] = (const unsigned*)(A + (size_t)gr * KP + lc * 8);
  }
  const unsigned* bptr[BN / 32];
#pragma unroll
  for (int p = 0; p < BN / 32; p++) {
    int rb = wv * (BN / 4) + p * 8 + lr;
    bptr[p] = (const unsigned*)(B + (size_t)(n0 + rb) * KP + lc * 8);
  }

  for (int kt = 0; kt < KP; kt += BK) {
    __syncthreads();
#pragma unroll
    for (int p = 0; p < BM / 32; p++)
      gld16(aptr[p] + (kt >> 1), (unsigned*)&As[(wv * (BM / 4) + p * 8) * BK]);
#pragma unroll
    for (int p = 0; p < BN / 32; p++)
      gld16(bptr[p] + (kt >> 1), (unsigned*)&Bs[(wv * (BN / 4) + p * 8) * BK]);
    __syncthreads();

    f16x8 fa[2][RM], fb[2][RN];
#pragma unroll
    for (int kk = 0; kk < 2; kk++) {
      int ch = ((kk * 4 + lq) ^ (lm & 7)) * 8;
#pragma unroll
      for (int mi = 0; mi < RM; mi++) {
        int ra = wm * WM + mi * 16 + lm;
        fa[kk][mi] = *(const f16x8*)&As[ra * BK + ch];
      }
#pragma unroll
      for (int ni = 0; ni < RN; ni++) {
        int rb = wn * WN + ni * 16 + lm;
        fb[kk][ni] = *(const f16x8*)&Bs[rb * BK + ch];
      }
    }
#pragma unroll
    for (int kk = 0; kk < 2; kk++)
#pragma unroll
      for (int mi = 0; mi < RM; mi++)
#pragma unroll
        for (int ni = 0; ni < RN; ni++)
          acc[mi][ni] = __builtin_amdgcn_mfma_f32_16x16x32_f16(
              fa[kk][mi], fb[kk][ni], acc[mi][ni], 0, 0, 0);
  }

  // C/D layout: col=lane&15 (=n), row=(lane>>4)*4+reg (=m)  [m89/m91]
#pragma unroll
  for (int ni = 0; ni < RN; ni++) {
    int n = n0 + wn * WN + ni * 16 + lm;
    float bv = bias[n];
#pragma unroll
    for (int mi = 0; mi < RM; mi++)
#pragma unroll
      for (int r = 0; r < 4; r++) {
        int m = m0 + wm * WM + mi * 16 + lq * 4 + r;
        if (m < M) {
          float val = acc[mi][ni][r] + bv;
          if constexpr (F16OUT)
            ((unsigned short*)Cv)[(size_t)m * N + n] = f2h(val);
          else
            ((float*)Cv)[(size_t)m * N + n] = val;
        }
      }
  }
}

// MFMA flash-window attention over fp16 qkv, with FUSED cls attention:
// each block's staged K/V rows (Ks 32..95 / Vt cols 32..95) form a disjoint
// 64-key chunk of the cls query's keyset, so the cls split-K partial is
// computed in-block from LDS; the last-arriving block per (b,h) (device-scope
// counter, threadfence) merges all 32 partials + the cls self-key in fixed
// order (bitwise-deterministic). Targeted LDS zero keeps the round-5
// residual-LDS bug class dead.
__global__ __launch_bounds__(256) void patch_attn4(
    const unsigned short* __restrict__ qkv16, unsigned short* __restrict__ Aatt,
    float* __restrict__ Pm, float* __restrict__ Pl, float* __restrict__ Po,
    unsigned* __restrict__ counters) {
  constexpr int LDK = 72;   // ushort stride for Ks (144 B rows, 16B-aligned)
  constexpr int LDT = 168;  // ushort stride for Vt/Ps (336 B rows)
  __shared__ __align__(16) unsigned short Ks[144 * LDK];  // 20.25 KB
  __shared__ __align__(16) unsigned short Vt[64 * LDT];   // 21 KB
  __shared__ __align__(16) unsigned short Ps[64 * LDT];   // 21 KB
  __shared__ float sbuf[64], ebuf[64];
  __shared__ int clsflag;

  const int t = threadIdx.x;
  const int qb = blockIdx.x;  // 0..15
  const int h = blockIdx.y;
  const int par = blockIdx.z & 1, b = blockIdx.z >> 1;
  const int lane = t & 63, wv = t >> 6;
  const int lm = lane & 15, lq = lane >> 4;
  const unsigned short* base = qkv16 + (size_t)b * S_LEN * 1536;
  const int qc0 = qb * 64;

  // ---- targeted zero: regions staging does not write ----
  {
    uint4 z = {0, 0, 0, 0};
    if (t < 135) {  // Ks rows 129..143
      int row = 129 + t / 9, q = t % 9;
      *(uint4*)&Ks[row * LDK + q * 8] = z;
    }
    {  // Vt cols 128..159
      int row = t >> 2, q = t & 3;
      *(uint4*)&Vt[row * LDT + 128 + q * 8] = z;
    }
    if (t < 128) {  // Ps cols 144..159
      int row = t >> 1, q = t & 1;
      *(uint4*)&Ps[row * LDT + 144 + q * 8] = z;
    }
  }
  __syncthreads();

  // ---- stage K (direct fp16 copy): window rows 0..127, cls row 128 ----
  {
    int rr = t >> 4;
    int cc = (t & 15) * 4;  // 4 halves (8 B) per thread
#pragma unroll
    for (int pass = 0; pass < 8; pass++) {
      int r = pass * 16 + rr;
      int jc = qc0 - 32 + r;
      uint2 kv = {0, 0};
      if ((unsigned)jc < 1024u)
        kv = *(const uint2*)(base + (size_t)(1 + 2 * jc + par) * 1536 + 512 +
                             h * 64 + cc);
      *(uint2*)&Ks[r * LDK + cc] = kv;
    }
    if (rr == 0)
      *(uint2*)&Ks[128 * LDK + cc] = *(const uint2*)(base + 512 + h * 64 + cc);
  }
  // ---- stage V transposed: Vt[d][jl] via half-pair repack ----
#pragma unroll
  for (int pass = 0; pass < 4; pass++) {
    int task = pass * 256 + t;
    int jp = task >> 4;        // jl pair 0..63
    int d0 = (task & 15) * 4;  // dim base
    int jc0 = qc0 - 32 + 2 * jp;
    uint2 a = {0, 0}, c = {0, 0};
    if ((unsigned)jc0 < 1024u)
      a = *(const uint2*)(base + (size_t)(1 + 2 * jc0 + par) * 1536 + 1024 +
                          h * 64 + d0);
    if ((unsigned)(jc0 + 1) < 1024u)
      c = *(const uint2*)(base + (size_t)(1 + 2 * (jc0 + 1) + par) * 1536 +
                          1024 + h * 64 + d0);
    *(unsigned*)&Vt[(d0 + 0) * LDT + 2 * jp] = (a.x & 0xffffu) | (c.x << 16);
    *(unsigned*)&Vt[(d0 + 1) * LDT + 2 * jp] = (a.x >> 16) | (c.x & 0xffff0000u);
    *(unsigned*)&Vt[(d0 + 2) * LDT + 2 * jp] = (a.y & 0xffffu) | (c.y << 16);
    *(unsigned*)&Vt[(d0 + 3) * LDT + 2 * jp] = (a.y >> 16) | (c.y & 0xffff0000u);
  }
  if (t < 64) Vt[t * LDT + 128] = base[1024 + h * 64 + t];  // cls V col

  // ---- Q fragment: direct f16x8 loads (A-frag: m=lane&15, k=quad*8+j) ----
  const int qi = wv * 16 + lm;
  const unsigned short* qg =
      base + (size_t)(1 + 2 * (qc0 + qi) + par) * 1536 + h * 64;
  f16x8 qf[2];
  qf[0] = *(const f16x8*)&qg[lq * 8];
  qf[1] = *(const f16x8*)&qg[32 + lq * 8];
  __syncthreads();

  // ---- S = Q·K^T : 9 N-tiles of 16 cols ----
  f32x4 s[9];
#pragma unroll
  for (int nt = 0; nt < 9; nt++) s[nt] = (f32x4){0.f, 0.f, 0.f, 0.f};
#pragma unroll
  for (int nt = 0; nt < 9; nt++) {
#pragma unroll
    for (int kk = 0; kk < 2; kk++) {
      f16x8 kb = *(const f16x8*)&Ks[(nt * 16 + lm) * LDK + kk * 32 + lq * 8];
      s[nt] =
          __builtin_amdgcn_mfma_f32_16x16x32_f16(qf[kk], kb, s[nt], 0, 0, 0);
    }
  }

  // ---- masked softmax per row; SCALE applied post-MFMA in fp32 ----
  float L[4];
#pragma unroll
  for (int r = 0; r < 4; r++) {
    int qrow = wv * 16 + lq * 4 + r;  // query index within 64-chunk
    float sv[9];
    float mx = -1e30f;
#pragma unroll
    for (int nt = 0; nt < 9; nt++) {
      int jl = nt * 16 + lm;
      bool valid =
          (jl == 128) ||
          (jl < 128 && jl >= qrow && jl <= qrow + 64 &&
           (unsigned)(qc0 - 32 + jl) < 1024u);
      sv[nt] = valid ? s[nt][r] * SCALE : -1e30f;
      mx = fmaxf(mx, sv[nt]);
    }
#pragma unroll
    for (int off = 1; off < 16; off <<= 1)
      mx = fmaxf(mx, __shfl_xor(mx, off, 16));
    float l = 0.f;
#pragma unroll
    for (int nt = 0; nt < 9; nt++) {
      float e = __expf(sv[nt] - mx);
      l += e;
      Ps[qrow * LDT + nt * 16 + lm] = f2h(e);
    }
#pragma unroll
    for (int off = 1; off < 16; off <<= 1) l += __shfl_xor(l, off, 16);
    L[r] = l;
  }
  __syncthreads();

  // ---- O = P·V : A=Ps rows (m=query), B=Vt rows (n=d), K=160 ----
  f32x4 oa[4];
#pragma unroll
  for (int nt = 0; nt < 4; nt++) oa[nt] = (f32x4){0.f, 0.f, 0.f, 0.f};
#pragma unroll
  for (int kc = 0; kc < 5; kc++) {
    f16x8 pa = *(const f16x8*)&Ps[(wv * 16 + lm) * LDT + kc * 32 + lq * 8];
#pragma unroll
    for (int nt = 0; nt < 4; nt++) {
      f16x8 vb = *(const f16x8*)&Vt[(nt * 16 + lm) * LDT + kc * 32 + lq * 8];
      oa[nt] = __builtin_amdgcn_mfma_f32_16x16x32_f16(pa, vb, oa[nt], 0, 0, 0);
    }
  }

  // ---- epilogue: normalize, write fp16 into Aatt[*, 512] ----
#pragma unroll
  for (int r = 0; r < 4; r++) {
    float inv = 1.f / L[r];
    int qrow = wv * 16 + lq * 4 + r;
    int pp = 2 * (qc0 + qrow) + par;
    unsigned short* ab = Aatt + ((size_t)b * S_LEN + 1 + pp) * 512 + h * 64;
#pragma unroll
    for (int nt = 0; nt < 4; nt++) ab[nt * 16 + lm] = f2h(oa[nt][r] * inv);
  }

  // ==== fused cls partial over this block's 64 keys (Ks rows 32..95) ====
  const int pidx = ((b * NH + h) * 2 + par) * 16 + qb;  // 0..511
  {
    int r = t >> 2, dq = t & 3;  // 4 threads per key row, 16 dims each
    float sp = 0.f;
#pragma unroll
    for (int j = 0; j < 16; j++)
      sp += h2f(base[h * 64 + dq * 16 + j]) *
            h2f(Ks[(32 + r) * LDK + dq * 16 + j]);
    sp += __shfl_xor(sp, 1, 4);
    sp += __shfl_xor(sp, 2, 4);
    if (dq == 0) sbuf[r] = sp * SCALE;
  }
  __syncthreads();
  if (wv == 0) {  // wave 0: max / exp / l over the 64 keys
    float sv = sbuf[lane];
    float mx = sv;
#pragma unroll
    for (int off = 32; off > 0; off >>= 1)
      mx = fmaxf(mx, __shfl_xor(mx, off, 64));
    float e = __expf(sv - mx);
    ebuf[lane] = e;
    float l = e;
#pragma unroll
    for (int off = 32; off > 0; off >>= 1) l += __shfl_xor(l, off, 64);
    if (lane == 0) {
      Pm[pidx] = mx;
      Pl[pidx] = l;
    }
    // o[d] = sum_r e_r * V[r][d]  (Vt cols 32..95), wave 0: lane = dim
    float o = 0.f;
    for (int r2 = 0; r2 < 64; r2++)
      o += ebuf[r2] * h2f(Vt[lane * LDT + 32 + r2]);
    Po[(size_t)pidx * 64 + lane] = o;
  }
  __syncthreads();  // drains vmcnt: all global partial writes complete
  if (t == 0) {
    __threadfence();  // release: partials visible device-wide before count
    unsigned old = atomicAdd(&counters[b * NH + h], 1u);
    clsflag = (old == 31);
  }
  __syncthreads();
  if (clsflag && t < 64) {  // last block: merge 32 partials + cls self-key
    __threadfence();        // acquire
    float m = -1e30f, l = 0.f, o = 0.f;
    int pb = (b * NH + h) * 32;
    for (int k = 0; k < 32; k++) {
      float mc = Pm[pb + k];
      float lc = Pl[pb + k];
      float oc = Po[(size_t)(pb + k) * 64 + t];
      float mn = fmaxf(m, mc);
      float e0 = __expf(m - mn);
      float e1 = __expf(mc - mn);
      l = l * e0 + lc * e1;
      o = o * e0 + oc * e1;
      m = mn;
    }
    // cls self-key (row 0): s0 = q_cls·k_cls * SCALE (wave-0 butterfly)
    float p = h2f(base[h * 64 + t]) * h2f(base[512 + h * 64 + t]);
#pragma unroll
    for (int off = 32; off > 0; off >>= 1) p += __shfl_xor(p, off, 64);
    float s0 = p * SCALE;
    float vv = h2f(base[1024 + h * 64 + t]);
    float mn = fmaxf(m, s0);
    float e0 = __expf(m - mn);
    float e1 = __expf(s0 - mn);
    l = l * e0 + e1;
    o = o * e0 + e1 * vv;
    Aatt[(size_t)b * S_LEN * 512 + h * 64 + t] = f2h(o / l);
  }
}

extern "C" void kernel_launch(void* const* d_in, const int* in_sizes, int n_in,
                              void* d_out, int out_size, void* d_ws,
                              size_t ws_size, hipStream_t stream) {
  const float* x = (const float*)d_in[0];
  const float* qkv_w = (const float*)d_in[1];
  const float* qkv_b = (const float*)d_in[2];
  const float* out_w = (const float*)d_in[3];
  const float* out_b = (const float*)d_in[4];
  float* out = (float*)d_out;

  const int M = 2 * S_LEN;  // 4098

  float* cls_pm = (float*)d_ws;                            // 512
  float* cls_pl = cls_pm + 512;                            // 512
  float* cls_po = cls_pl + 512;                            // 32768
  unsigned* counters = (unsigned*)(cls_po + 32768);        // 16
  unsigned short* Xp = (unsigned short*)(counters + 16);   // 4098*512 fp16
  unsigned short* Wq = Xp + (size_t)M * 512;               // 1536*512 fp16
  unsigned short* Wo = Wq + (size_t)1536 * 512;            // 512*512 fp16
  unsigned short* Aatt = Wo + (size_t)512 * 512;           // 4098*512 fp16
  unsigned short* qkv16 = Aatt + (size_t)M * 512;          // 4098*1536 fp16

  const int n0 = M * EMB;     // 2098176
  const int n1 = 1536 * EMB;  // 786432
  const int n2 = EMB * EMB;   // 262144
  int cvt_blocks = ((n0 + n1 + n2) / 8 + 255) / 256;
  cvt3_f16<<<cvt_blocks, 256, 0, stream>>>(x, Xp, n0, qkv_w, Wq, n1, out_w, Wo,
                                           n2, counters);

  // QKV projection: fp16 GEMM K=512 (BK=64), fp16 output
  dim3 gq((M + 63) / 64, 1536 / 128);  // 65 x 12 = 780 blocks
  gemm_f16<64, 128, true><<<gq, 256, 0, stream>>>(Xp, Wq, qkv_b, qkv16, M,
                                                  1536, 512);

  // attention + fused cls split-K (partials + last-block combine)
  patch_attn4<<<dim3(16, NH, 4), 256, 0, stream>>>(qkv16, Aatt, cls_pm, cls_pl,
                                                   cls_po, counters);

  // Output projection: fp16 GEMM K=512 (BK=64), fp32 output
  dim3 go((M + 63) / 64, EMB / 64);  // 65 x 8 = 520 blocks
  gemm_f16<64, 64, false><<<go, 256, 0, stream>>>(Aatt, Wo, out_b, out, M, EMB,
                                                  512);
}

// Round 13
// 122.245 us; speedup vs baseline: 1.1088x; 1.1088x over previous
//
#include <hip/hip_runtime.h>
#include <math.h>

#define S_LEN 2049
#define P_LEN 2048
#define EMB 512
#define NH 8
#define HD 64
#define SCALE 0.125f

typedef _Float16 f16x8 __attribute__((ext_vector_type(8)));
typedef float f32x4 __attribute__((ext_vector_type(4)));
typedef unsigned short u16x8 __attribute__((ext_vector_type(8)));

__device__ inline unsigned short f2h(float f) {
  _Float16 h = (_Float16)f;  // RNE
  return __builtin_bit_cast(unsigned short, h);
}
__device__ inline float h2f(unsigned short u) {
  return (float)__builtin_bit_cast(_Float16, u);
}

__device__ inline float wave_sum64(float v) {
#pragma unroll
  for (int off = 32; off > 0; off >>= 1) v += __shfl_xor(v, off, 64);
  return v;
}

// async global->LDS, 16B per lane; LDS dest = wave-uniform base + lane*16
__device__ inline void gld16(const unsigned* g, unsigned* l) {
  __builtin_amdgcn_global_load_lds(
      (const __attribute__((address_space(1))) unsigned*)g,
      (__attribute__((address_space(3))) unsigned*)l, 16, 0, 0);
}

// fused fp32 -> fp16 converter for the three operands (x, qkv_w, out_w).
__global__ __launch_bounds__(256) void cvt3_f16(
    const float* __restrict__ s0, unsigned short* __restrict__ d0, int n0,
    const float* __restrict__ s1, unsigned short* __restrict__ d1, int n1,
    const float* __restrict__ s2, unsigned short* __restrict__ d2, int n2) {
  int idx = (blockIdx.x * 256 + threadIdx.x) * 8;
  const float* s;
  unsigned short* d;
  int off;
  if (idx < n0) {
    s = s0; d = d0; off = idx;
  } else if (idx < n0 + n1) {
    s = s1; d = d1; off = idx - n0;
  } else if (idx < n0 + n1 + n2) {
    s = s2; d = d2; off = idx - n0 - n1;
  } else {
    return;
  }
  float4 f0 = *(const float4*)(s + off);
  float4 f1 = *(const float4*)(s + off + 4);
  float ff[8] = {f0.x, f0.y, f0.z, f0.w, f1.x, f1.y, f1.z, f1.w};
  u16x8 vh;
#pragma unroll
  for (int e = 0; e < 8; e++) vh[e] = f2h(ff[e]);
  *(u16x8*)(d + off) = vh;
}

// Plain fp16 GEMM, m97 structure, BK=64 (proven best: BK=128 regressed
// round-10 per m132; atomic-fused variants regressed round-12).
template <int BM, int BN, bool F16OUT>
__global__ __launch_bounds__(256) void gemm_f16(
    const unsigned short* __restrict__ A, const unsigned short* __restrict__ B,
    const float* __restrict__ bias, void* __restrict__ Cv, int M, int N,
    int KP) {
  constexpr int BK = 64;
  __shared__ __align__(16) unsigned short As[BM * BK];
  __shared__ __align__(16) unsigned short Bs[BN * BK];
  const int t = threadIdx.x;
  const int lane = t & 63, wv = t >> 6;
  const int m0 = blockIdx.x * BM, n0 = blockIdx.y * BN;
  constexpr int WM = BM / 2, WN = BN / 2;
  constexpr int RM = WM / 16, RN = WN / 16;
  const int wm = wv & 1, wn = wv >> 1;
  const int lm = lane & 15, lq = lane >> 4;

  f32x4 acc[RM][RN];
#pragma unroll
  for (int i = 0; i < RM; i++)
#pragma unroll
    for (int j = 0; j < RN; j++) acc[i][j] = (f32x4){0.f, 0.f, 0.f, 0.f};

  const int lr = lane >> 3;
  const int lc = (lane & 7) ^ lr;  // XOR-swizzled source chunk (bank spread)

  const unsigned* aptr[BM / 32];
#pragma unroll
  for (int p = 0; p < BM / 32; p++) {
    int ra = wv * (BM / 4) + p * 8 + lr;
    int gr = m0 + ra;
    gr = gr < M ? gr : M - 1;  // clamp source (epilogue store is guarded)
    aptr[p] = (const unsigned*)(A + (size_t)gr * KP + lc * 8);
  }
  const unsigned* bptr[BN / 32];
#pragma unroll
  for (int p = 0; p < BN / 32; p++) {
    int rb = wv * (BN / 4) + p * 8 + lr;
    bptr[p] = (const unsigned*)(B + (size_t)(n0 + rb) * KP + lc * 8);
  }

  for (int kt = 0; kt < KP; kt += BK) {
    __syncthreads();
#pragma unroll
    for (int p = 0; p < BM / 32; p++)
      gld16(aptr[p] + (kt >> 1), (unsigned*)&As[(wv * (BM / 4) + p * 8) * BK]);
#pragma unroll
    for (int p = 0; p < BN / 32; p++)
      gld16(bptr[p] + (kt >> 1), (unsigned*)&Bs[(wv * (BN / 4) + p * 8) * BK]);
    __syncthreads();

    f16x8 fa[2][RM], fb[2][RN];
#pragma unroll
    for (int kk = 0; kk < 2; kk++) {
      int ch = ((kk * 4 + lq) ^ (lm & 7)) * 8;
#pragma unroll
      for (int mi = 0; mi < RM; mi++) {
        int ra = wm * WM + mi * 16 + lm;
        fa[kk][mi] = *(const f16x8*)&As[ra * BK + ch];
      }
#pragma unroll
      for (int ni = 0; ni < RN; ni++) {
        int rb = wn * WN + ni * 16 + lm;
        fb[kk][ni] = *(const f16x8*)&Bs[rb * BK + ch];
      }
    }
#pragma unroll
    for (int kk = 0; kk < 2; kk++)
#pragma unroll
      for (int mi = 0; mi < RM; mi++)
#pragma unroll
        for (int ni = 0; ni < RN; ni++)
          acc[mi][ni] = __builtin_amdgcn_mfma_f32_16x16x32_f16(
              fa[kk][mi], fb[kk][ni], acc[mi][ni], 0, 0, 0);
  }

  // C/D layout: col=lane&15 (=n), row=(lane>>4)*4+reg (=m)  [m89/m91]
#pragma unroll
  for (int ni = 0; ni < RN; ni++) {
    int n = n0 + wn * WN + ni * 16 + lm;
    float bv = bias[n];
#pragma unroll
    for (int mi = 0; mi < RM; mi++)
#pragma unroll
      for (int r = 0; r < 4; r++) {
        int m = m0 + wm * WM + mi * 16 + lq * 4 + r;
        if (m < M) {
          float val = acc[mi][ni][r] + bv;
          if constexpr (F16OUT)
            ((unsigned short*)Cv)[(size_t)m * N + n] = f2h(val);
          else
            ((float*)Cv)[(size_t)m * N + n] = val;
        }
      }
  }
}

// MFMA flash-window attention over fp16 qkv. LDS fully zeroed before staging
// (round-5/7 lesson: residual-LDS reads caused post-timing divergence).
__global__ __launch_bounds__(256) void patch_attn3(
    const unsigned short* __restrict__ qkv16,
    unsigned short* __restrict__ Aatt) {
  constexpr int LDK = 72;   // ushort stride for Ks (144 B rows, 16B-aligned)
  constexpr int LDT = 168;  // ushort stride for Vt/Ps
  __shared__ __align__(16) unsigned short Ks[144 * LDK];  // 20.25 KB
  __shared__ __align__(16) unsigned short Vt[64 * LDT];   // 21 KB
  __shared__ __align__(16) unsigned short Ps[64 * LDT];   // 21 KB

  const int t = threadIdx.x;
  const int lane = t & 63, wv = t >> 6;
  const int lm = lane & 15, lq = lane >> 4;
  const int qb = blockIdx.x;  // 0..15
  const int h = blockIdx.y;
  const int par = blockIdx.z & 1, b = blockIdx.z >> 1;
  const unsigned short* base = qkv16 + (size_t)b * S_LEN * 1536;
  const int qc0 = qb * 64;

  // ---- defensive zero of ALL LDS ----
  {
    uint4 z = {0, 0, 0, 0};
    for (int i = t; i < 144 * LDK / 8; i += 256) ((uint4*)Ks)[i] = z;
    for (int i = t; i < 64 * LDT / 8; i += 256) ((uint4*)Vt)[i] = z;
    for (int i = t; i < 64 * LDT / 8; i += 256) ((uint4*)Ps)[i] = z;
  }
  __syncthreads();

  // ---- stage K (direct fp16 copy): window rows 0..127, cls row 128 ----
  {
    int rr = t >> 4;
    int cc = (t & 15) * 4;  // 4 halves (8 B) per thread
#pragma unroll
    for (int pass = 0; pass < 8; pass++) {
      int r = pass * 16 + rr;
      int jc = qc0 - 32 + r;
      uint2 kv = {0, 0};
      if ((unsigned)jc < 1024u)
        kv = *(const uint2*)(base + (size_t)(1 + 2 * jc + par) * 1536 + 512 +
                             h * 64 + cc);
      *(uint2*)&Ks[r * LDK + cc] = kv;
    }
    if (rr == 0)
      *(uint2*)&Ks[128 * LDK + cc] =
          *(const uint2*)(base + 512 + h * 64 + cc);
  }
  // ---- stage V transposed: Vt[d][jl] via half-pair repack ----
#pragma unroll
  for (int pass = 0; pass < 4; pass++) {
    int task = pass * 256 + t;
    int jp = task >> 4;        // jl pair 0..63
    int d0 = (task & 15) * 4;  // dim base
    int jc0 = qc0 - 32 + 2 * jp;
    uint2 a = {0, 0}, c = {0, 0};
    if ((unsigned)jc0 < 1024u)
      a = *(const uint2*)(base + (size_t)(1 + 2 * jc0 + par) * 1536 + 1024 +
                          h * 64 + d0);
    if ((unsigned)(jc0 + 1) < 1024u)
      c = *(const uint2*)(base + (size_t)(1 + 2 * (jc0 + 1) + par) * 1536 +
                          1024 + h * 64 + d0);
    *(unsigned*)&Vt[(d0 + 0) * LDT + 2 * jp] = (a.x & 0xffffu) | (c.x << 16);
    *(unsigned*)&Vt[(d0 + 1) * LDT + 2 * jp] = (a.x >> 16) | (c.x & 0xffff0000u);
    *(unsigned*)&Vt[(d0 + 2) * LDT + 2 * jp] = (a.y & 0xffffu) | (c.y << 16);
    *(unsigned*)&Vt[(d0 + 3) * LDT + 2 * jp] = (a.y >> 16) | (c.y & 0xffff0000u);
  }
  if (t < 64) Vt[t * LDT + 128] = base[1024 + h * 64 + t];  // cls V col

  // ---- Q fragment: direct f16x8 loads (A-frag: m=lane&15, k=quad*8+j) ----
  const int qi = wv * 16 + lm;
  const unsigned short* qg =
      base + (size_t)(1 + 2 * (qc0 + qi) + par) * 1536 + h * 64;
  f16x8 qf[2];
  qf[0] = *(const f16x8*)&qg[lq * 8];
  qf[1] = *(const f16x8*)&qg[32 + lq * 8];
  __syncthreads();

  // ---- S = Q·K^T : 9 N-tiles of 16 cols ----
  f32x4 s[9];
#pragma unroll
  for (int nt = 0; nt < 9; nt++) s[nt] = (f32x4){0.f, 0.f, 0.f, 0.f};
#pragma unroll
  for (int nt = 0; nt < 9; nt++) {
#pragma unroll
    for (int kk = 0; kk < 2; kk++) {
      f16x8 kb = *(const f16x8*)&Ks[(nt * 16 + lm) * LDK + kk * 32 + lq * 8];
      s[nt] =
          __builtin_amdgcn_mfma_f32_16x16x32_f16(qf[kk], kb, s[nt], 0, 0, 0);
    }
  }

  // ---- masked softmax per row; SCALE applied post-MFMA in fp32 ----
  float L[4];
#pragma unroll
  for (int r = 0; r < 4; r++) {
    int qrow = wv * 16 + lq * 4 + r;  // query index within 64-chunk
    float sv[9];
    float mx = -1e30f;
#pragma unroll
    for (int nt = 0; nt < 9; nt++) {
      int jl = nt * 16 + lm;
      bool valid =
          (jl == 128) ||
          (jl < 128 && jl >= qrow && jl <= qrow + 64 &&
           (unsigned)(qc0 - 32 + jl) < 1024u);
      sv[nt] = valid ? s[nt][r] * SCALE : -1e30f;
      mx = fmaxf(mx, sv[nt]);
    }
#pragma unroll
    for (int off = 1; off < 16; off <<= 1)
      mx = fmaxf(mx, __shfl_xor(mx, off, 16));
    float l = 0.f;
#pragma unroll
    for (int nt = 0; nt < 9; nt++) {
      float e = __expf(sv[nt] - mx);
      l += e;
      Ps[qrow * LDT + nt * 16 + lm] = f2h(e);
    }
#pragma unroll
    for (int off = 1; off < 16; off <<= 1) l += __shfl_xor(l, off, 16);
    L[r] = l;
  }
  __syncthreads();

  // ---- O = P·V : A=Ps rows (m=query), B=Vt rows (n=d), K=160 ----
  f32x4 oa[4];
#pragma unroll
  for (int nt = 0; nt < 4; nt++) oa[nt] = (f32x4){0.f, 0.f, 0.f, 0.f};
#pragma unroll
  for (int kc = 0; kc < 5; kc++) {
    f16x8 pa = *(const f16x8*)&Ps[(wv * 16 + lm) * LDT + kc * 32 + lq * 8];
#pragma unroll
    for (int nt = 0; nt < 4; nt++) {
      f16x8 vb = *(const f16x8*)&Vt[(nt * 16 + lm) * LDT + kc * 32 + lq * 8];
      oa[nt] = __builtin_amdgcn_mfma_f32_16x16x32_f16(pa, vb, oa[nt], 0, 0, 0);
    }
  }

  // ---- epilogue: normalize, write fp16 into Aatt[*, 512] ----
#pragma unroll
  for (int r = 0; r < 4; r++) {
    float inv = 1.f / L[r];
    int qrow = wv * 16 + lq * 4 + r;
    int pp = 2 * (qc0 + qrow) + par;
    unsigned short* ab = Aatt + ((size_t)b * S_LEN + 1 + pp) * 512 + h * 64;
#pragma unroll
    for (int nt = 0; nt < 4; nt++) ab[nt * 16 + lm] = f2h(oa[nt][r] * inv);
  }
}

// CLS attention, split-K stage 1 (fp16 qkv inputs).
__global__ __launch_bounds__(256) void cls_part_k(
    const unsigned short* __restrict__ qkv16, float* __restrict__ Pm,
    float* __restrict__ Pl, float* __restrict__ Po) {
  const int lane = threadIdx.x & 63;
  const int wv = threadIdx.x >> 6;
  const int ck = blockIdx.x;
  const int h = blockIdx.y;
  const int b = blockIdx.z;
  const unsigned short* base = qkv16 + (size_t)b * S_LEN * 1536;
  float qd = h2f(base[h * 64 + lane]) * SCALE;

  int c0 = ck * 64;
  int cend = (ck == 31) ? S_LEN : c0 + 64;

  float m = -1e30f, l = 0.f, o = 0.f;
  for (int j = c0 + wv; j < cend; j += 4) {
    const unsigned short* krow = base + (size_t)j * 1536 + 512 + h * 64;
    float kv = h2f(krow[lane]);
    float vv = h2f(krow[512 + lane]);
    float s = wave_sum64(qd * kv);
    float mn = fmaxf(m, s);
    float e0 = __expf(m - mn);
    float e1 = __expf(s - mn);
    l = l * e0 + e1;
    o = o * e0 + e1 * vv;
    m = mn;
  }

  __shared__ float sm[4], sl[4], so[4][64];
  if (lane == 0) {
    sm[wv] = m;
    sl[wv] = l;
  }
  so[wv][lane] = o;
  __syncthreads();
  if (wv == 0) {
    float M = -1e30f;
#pragma unroll
    for (int i = 0; i < 4; i++) M = fmaxf(M, sm[i]);
    float L = 0.f, O = 0.f;
#pragma unroll
    for (int i = 0; i < 4; i++) {
      float c = __expf(sm[i] - M);
      L += sl[i] * c;
      O += so[i][lane] * c;
    }
    int idx = (b * NH + h) * 32 + ck;
    if (lane == 0) {
      Pm[idx] = M;
      Pl[idx] = L;
    }
    Po[(size_t)idx * 64 + lane] = O;
  }
}

// CLS split-K stage 2: combine partials; write fp16 into Aatt row 0.
__global__ __launch_bounds__(64) void cls_comb_k(
    const float* __restrict__ Pm, const float* __restrict__ Pl,
    const float* __restrict__ Po, unsigned short* __restrict__ Aatt) {
  const int lane = threadIdx.x;
  const int h = blockIdx.x % NH;
  const int b = blockIdx.x / NH;
  float m = -1e30f, l = 0.f, o = 0.f;
  for (int ck = 0; ck < 32; ck++) {
    int idx = (b * NH + h) * 32 + ck;
    float mc = Pm[idx];
    float lc = Pl[idx];
    float oc = Po[(size_t)idx * 64 + lane];
    float mn = fmaxf(m, mc);
    float e0 = __expf(m - mn);
    float e1 = __expf(mc - mn);
    l = l * e0 + lc * e1;
    o = o * e0 + oc * e1;
    m = mn;
  }
  Aatt[(size_t)b * S_LEN * 512 + h * HD + lane] = f2h(o / l);
}

extern "C" void kernel_launch(void* const* d_in, const int* in_sizes, int n_in,
                              void* d_out, int out_size, void* d_ws,
                              size_t ws_size, hipStream_t stream) {
  const float* x = (const float*)d_in[0];
  const float* qkv_w = (const float*)d_in[1];
  const float* qkv_b = (const float*)d_in[2];
  const float* out_w = (const float*)d_in[3];
  const float* out_b = (const float*)d_in[4];
  float* out = (float*)d_out;

  const int M = 2 * S_LEN;  // 4098

  float* cls_pm = (float*)d_ws;                            // 512
  float* cls_pl = cls_pm + 512;                            // 512
  float* cls_po = cls_pl + 512;                            // 32768
  unsigned short* Xp = (unsigned short*)(cls_po + 32768);  // 4098*512 fp16
  unsigned short* Wq = Xp + (size_t)M * 512;               // 1536*512 fp16
  unsigned short* Wo = Wq + (size_t)1536 * 512;            // 512*512 fp16
  unsigned short* Aatt = Wo + (size_t)512 * 512;           // 4098*512 fp16
  unsigned short* qkv16 = Aatt + (size_t)M * 512;          // 4098*1536 fp16

  const int n0 = M * EMB;     // 2098176
  const int n1 = 1536 * EMB;  // 786432
  const int n2 = EMB * EMB;   // 262144
  int cvt_blocks = ((n0 + n1 + n2) / 8 + 255) / 256;
  cvt3_f16<<<cvt_blocks, 256, 0, stream>>>(x, Xp, n0, qkv_w, Wq, n1, out_w, Wo,
                                           n2);

  // QKV projection: fp16 GEMM K=512 (BK=64), fp16 output
  dim3 gq((M + 63) / 64, 1536 / 128);  // 65 x 12 = 780 blocks
  gemm_f16<64, 128, true><<<gq, 256, 0, stream>>>(Xp, Wq, qkv_b, qkv16, M,
                                                  1536, 512);

  cls_part_k<<<dim3(32, NH, 2), 256, 0, stream>>>(qkv16, cls_pm, cls_pl,
                                                  cls_po);
  cls_comb_k<<<2 * NH, 64, 0, stream>>>(cls_pm, cls_pl, cls_po, Aatt);
  patch_attn3<<<dim3(16, NH, 4), 256, 0, stream>>>(qkv16, Aatt);

  // Output projection: fp16 GEMM K=512 (BK=64), fp32 output
  dim3 go((M + 63) / 64, EMB / 64);  // 65 x 8 = 520 blocks
  gemm_f16<64, 64, false><<<go, 256, 0, stream>>>(Aatt, Wo, out_b, out, M, EMB,
                                                  512);
}